// Round 1
// baseline (716.945 us; speedup 1.0000x reference)
//
#include <hip/hip_runtime.h>

#define N_NODES 100000
#define NEDGE   3200000
#define F_IN    512
#define HID     16
#define NCLS    40
#define SCAN_CHUNK 1024
#define NB ((N_NODES + SCAN_CHUNK - 1) / SCAN_CHUNK)  /* 98 */

typedef __bf16 bf16x8 __attribute__((ext_vector_type(8)));
typedef float floatx4 __attribute__((ext_vector_type(4)));

// ---------------- degree histogram (in-degree over dst) ----------------
__global__ void k_deg(const int* __restrict__ dst, int* __restrict__ deg) {
    int e = blockIdx.x * 256 + threadIdx.x;
    if (e < NEDGE) atomicAdd(&deg[dst[e]], 1);
}

// dinv = rsqrt(deg + 1)  (+1 = self loop)
__global__ void k_dinv(const int* __restrict__ deg, float* __restrict__ dinv) {
    int v = blockIdx.x * 256 + threadIdx.x;
    if (v < N_NODES) dinv[v] = rsqrtf((float)(deg[v] + 1));
}

// ---------------- hierarchical exclusive scan of deg -> rowptr ----------------
__global__ void k_scan_a(const int* __restrict__ deg, int* __restrict__ bsum) {
    int b = blockIdx.x, t = threadIdx.x;
    int idx = b * SCAN_CHUNK + t * 4;
    int s = 0;
    #pragma unroll
    for (int j = 0; j < 4; j++) s += (idx + j < N_NODES) ? deg[idx + j] : 0;
    __shared__ int red[256];
    red[t] = s; __syncthreads();
    for (int off = 128; off; off >>= 1) {
        if (t < off) red[t] += red[t + off];
        __syncthreads();
    }
    if (t == 0) bsum[b] = red[0];
}

__global__ void k_scan_b(const int* __restrict__ bsum, int* __restrict__ boff,
                         int* __restrict__ rowptr) {
    int t = threadIdx.x;
    int v = (t < NB) ? bsum[t] : 0;
    __shared__ int sc[128];
    sc[t] = v; __syncthreads();
    for (int off = 1; off < 128; off <<= 1) {
        int add = (t >= off) ? sc[t - off] : 0;
        __syncthreads();
        sc[t] += add;
        __syncthreads();
    }
    if (t < NB) boff[t] = sc[t] - v;       // exclusive block offset
    if (t == NB - 1) rowptr[N_NODES] = sc[t];  // total == NEDGE
}

__global__ void k_scan_c(const int* __restrict__ deg, const int* __restrict__ boff,
                         int* __restrict__ rowptr) {
    int b = blockIdx.x, t = threadIdx.x;
    int idx = b * SCAN_CHUNK + t * 4;
    int d0 = (idx + 0 < N_NODES) ? deg[idx + 0] : 0;
    int d1 = (idx + 1 < N_NODES) ? deg[idx + 1] : 0;
    int d2 = (idx + 2 < N_NODES) ? deg[idx + 2] : 0;
    int d3 = (idx + 3 < N_NODES) ? deg[idx + 3] : 0;
    int local = d0 + d1 + d2 + d3;
    __shared__ int sc[256];
    sc[t] = local; __syncthreads();
    for (int off = 1; off < 256; off <<= 1) {
        int add = (t >= off) ? sc[t - off] : 0;
        __syncthreads();
        sc[t] += add;
        __syncthreads();
    }
    int start = boff[b] + sc[t] - local;   // exclusive prefix
    if (idx + 0 < N_NODES) rowptr[idx + 0] = start;
    if (idx + 1 < N_NODES) rowptr[idx + 1] = start + d0;
    if (idx + 2 < N_NODES) rowptr[idx + 2] = start + d0 + d1;
    if (idx + 3 < N_NODES) rowptr[idx + 3] = start + d0 + d1 + d2;
}

// ---------------- CSR fill: col[slot] = src, bucketed by dst ----------------
__global__ void k_fill(const int* __restrict__ src, const int* __restrict__ dst,
                       const int* __restrict__ rowptr, int* __restrict__ fill,
                       int* __restrict__ col) {
    int e = blockIdx.x * 256 + threadIdx.x;
    if (e < NEDGE) {
        int d = dst[e];
        int pos = rowptr[d] + atomicAdd(&fill[d], 1);
        col[pos] = src[e];
    }
}

// ---------------- GEMM1: h1s = dinv * (x @ W1), bf16 MFMA hi/lo split ----------------
// wave handles 16 rows; K=512 in 16 chunks of 32; A from global, B(W1) from LDS frags.
__global__ __launch_bounds__(256) void k_gemm1(const float* __restrict__ x,
                                               const float* __restrict__ W1,
                                               const float* __restrict__ dinv,
                                               float* __restrict__ h1s) {
    __shared__ __bf16 wh[16 * 64 * 8];
    __shared__ __bf16 wl[16 * 64 * 8];
    int t = threadIdx.x;
    // stage W1 into MFMA B-fragment layout: entry e=(c*64+lane)*8+j holds
    // W1[k=c*32+(lane>>4)*8+j][n=lane&15]
    for (int e = t; e < 8192; e += 256) {
        int c = e >> 9, l = (e >> 3) & 63, j = e & 7;
        int k = c * 32 + ((l >> 4) << 3) + j;
        int n = l & 15;
        float wv = W1[k * HID + n];
        __bf16 h = (__bf16)wv;
        wh[e] = h;
        wl[e] = (__bf16)(wv - (float)h);
    }
    __syncthreads();

    int wave = t >> 6, lane = t & 63;
    int q = lane >> 4, m = lane & 15;
    int row0 = blockIdx.x * 64 + wave * 16;
    int rowa = row0 + m;
    if (rowa >= N_NODES) rowa = N_NODES - 1;  // clamp (stores are guarded)
    const float* xr = x + (size_t)rowa * F_IN + q * 8;

    floatx4 acc = {0.f, 0.f, 0.f, 0.f};
    #pragma unroll 4
    for (int c = 0; c < 16; c++) {
        float4 a0 = *(const float4*)(xr + c * 32);
        float4 a1 = *(const float4*)(xr + c * 32 + 4);
        float xv[8] = {a0.x, a0.y, a0.z, a0.w, a1.x, a1.y, a1.z, a1.w};
        bf16x8 ah, al;
        #pragma unroll
        for (int j = 0; j < 8; j++) {
            __bf16 h = (__bf16)xv[j];
            ah[j] = h;
            al[j] = (__bf16)(xv[j] - (float)h);
        }
        bf16x8 bh = *(const bf16x8*)&wh[(c * 64 + lane) * 8];
        bf16x8 bl = *(const bf16x8*)&wl[(c * 64 + lane) * 8];
        acc = __builtin_amdgcn_mfma_f32_16x16x32_bf16(ah, bh, acc, 0, 0, 0);
        acc = __builtin_amdgcn_mfma_f32_16x16x32_bf16(ah, bl, acc, 0, 0, 0);
        acc = __builtin_amdgcn_mfma_f32_16x16x32_bf16(al, bh, acc, 0, 0, 0);
    }
    // C/D layout: col = lane&15, row = (lane>>4)*4 + r   [m89-verified]
    #pragma unroll
    for (int r = 0; r < 4; r++) {
        int grow = row0 + q * 4 + r;
        if (grow < N_NODES) h1s[grow * HID + (lane & 15)] = dinv[grow] * acc[r];
    }
}

// ---------------- layer-1 aggregate + bias + relu; output pre-scaled by dinv ----------------
__global__ void k_agg1(const float* __restrict__ h1s, const int* __restrict__ rowptr,
                       const int* __restrict__ col, const float* __restrict__ dinv,
                       const float* __restrict__ b1, float* __restrict__ ys) {
    int g = blockIdx.x * 256 + threadIdx.x;   // grid == N*16 exactly
    int v = g >> 4, k = g & 15;
    float sum = h1s[v * HID + k];             // self loop (h1s already dinv-scaled)
    int beg = rowptr[v], end = rowptr[v + 1];
    int j = beg;
    for (; j + 1 < end; j += 2) {
        int c0 = col[j], c1 = col[j + 1];
        float g0 = h1s[c0 * HID + k];
        float g1 = h1s[c1 * HID + k];
        sum += g0 + g1;
    }
    if (j < end) sum += h1s[col[j] * HID + k];
    float dv = dinv[v];
    float val = fmaxf(dv * sum + b1[k], 0.f);
    ys[v * HID + k] = dv * val;               // pre-scale for layer 2
}

// ---------------- layer-2 aggregate + W2 (16->40) + bias + log_softmax ----------------
__global__ void k_agg2(const float* __restrict__ ys, const int* __restrict__ rowptr,
                       const int* __restrict__ col, const float* __restrict__ dinv,
                       const float* __restrict__ W2, const float* __restrict__ b2,
                       float* __restrict__ out) {
    __shared__ float w2s[HID * NCLS];
    __shared__ float b2s[NCLS];
    int t = threadIdx.x;
    for (int i = t; i < HID * NCLS; i += 256) w2s[i] = W2[i];
    if (t < NCLS) b2s[t] = b2[t];
    __syncthreads();

    int g = blockIdx.x * 256 + t;             // grid == N*16 exactly
    int v = g >> 4, l = g & 15;
    float sum = ys[v * HID + l];              // self loop
    int beg = rowptr[v], end = rowptr[v + 1];
    int j = beg;
    for (; j + 1 < end; j += 2) {
        int c0 = col[j], c1 = col[j + 1];
        float g0 = ys[c0 * HID + l];
        float g1 = ys[c1 * HID + l];
        sum += g0 + g1;
    }
    if (j < end) sum += ys[col[j] * HID + l];
    float tval = dinv[v] * sum;               // aggregated feature l

    // 16->40 matvec: lane l covers classes {l, l+16, l+32(l<8)}
    float acc0 = 0.f, acc1 = 0.f, acc2 = 0.f;
    #pragma unroll
    for (int k = 0; k < 16; k++) {
        float tk = __shfl(tval, k, 16);
        acc0 = fmaf(tk, w2s[k * NCLS + l], acc0);
        acc1 = fmaf(tk, w2s[k * NCLS + l + 16], acc1);
        if (l < 8) acc2 = fmaf(tk, w2s[k * NCLS + l + 32], acc2);
    }
    acc0 += b2s[l];
    acc1 += b2s[l + 16];
    float acc2b = (l < 8) ? (acc2 + b2s[l + 32]) : -1e30f;

    // group softmax over the 40 logits spread across 16 lanes
    float mx = fmaxf(fmaxf(acc0, acc1), acc2b);
    for (int off = 8; off; off >>= 1) mx = fmaxf(mx, __shfl_xor(mx, off, 16));
    float s = __expf(acc0 - mx) + __expf(acc1 - mx) + __expf(acc2b - mx);
    for (int off = 8; off; off >>= 1) s += __shfl_xor(s, off, 16);
    float lse = mx + __logf(s);

    out[v * NCLS + l] = acc0 - lse;
    out[v * NCLS + l + 16] = acc1 - lse;
    if (l < 8) out[v * NCLS + l + 32] = acc2b - lse;
}

extern "C" void kernel_launch(void* const* d_in, const int* in_sizes, int n_in,
                              void* d_out, int out_size, void* d_ws, size_t ws_size,
                              hipStream_t stream) {
    const float* x  = (const float*)d_in[0];
    const int*   ei = (const int*)d_in[1];
    const float* W1 = (const float*)d_in[2];
    const float* b1 = (const float*)d_in[3];
    const float* W2 = (const float*)d_in[4];
    const float* b2 = (const float*)d_in[5];
    float* out = (float*)d_out;
    const int* src = ei;
    const int* dst = ei + NEDGE;

    char* w = (char*)d_ws;
    size_t o = 0;
    auto alloc = [&](size_t bytes) -> char* {
        char* p = w + o;
        o += (bytes + 511) & ~(size_t)511;
        return p;
    };
    int*   deg    = (int*)alloc((size_t)N_NODES * 4);
    float* dinv   = (float*)alloc((size_t)N_NODES * 4);
    int*   rowptr = (int*)alloc((size_t)(N_NODES + 1) * 4);
    int*   fill   = (int*)alloc((size_t)N_NODES * 4);
    int*   bsum   = (int*)alloc((size_t)NB * 4);
    int*   boff   = (int*)alloc((size_t)NB * 4);
    int*   col    = (int*)alloc((size_t)NEDGE * 4);
    float* h1s    = (float*)alloc((size_t)N_NODES * HID * 4);
    float* ys     = (float*)alloc((size_t)N_NODES * HID * 4);

    hipMemsetAsync(deg, 0, (size_t)N_NODES * 4, stream);
    hipMemsetAsync(fill, 0, (size_t)N_NODES * 4, stream);

    k_deg<<<NEDGE / 256, 256, 0, stream>>>(dst, deg);
    k_dinv<<<(N_NODES + 255) / 256, 256, 0, stream>>>(deg, dinv);
    k_scan_a<<<NB, 256, 0, stream>>>(deg, bsum);
    k_scan_b<<<1, 128, 0, stream>>>(bsum, boff, rowptr);
    k_scan_c<<<NB, 256, 0, stream>>>(deg, boff, rowptr);
    k_fill<<<NEDGE / 256, 256, 0, stream>>>(src, dst, rowptr, fill, col);
    k_gemm1<<<(N_NODES + 63) / 64, 256, 0, stream>>>(x, W1, dinv, h1s);
    k_agg1<<<(N_NODES * HID) / 256, 256, 0, stream>>>(h1s, rowptr, col, dinv, b1, ys);
    k_agg2<<<(N_NODES * HID) / 256, 256, 0, stream>>>(ys, rowptr, col, dinv, W2, b2, out);
}

// Round 3
// 710.018 us; speedup vs baseline: 1.0098x; 1.0098x over previous
//
#include <hip/hip_runtime.h>

#define N_NODES 100000
#define NEDGE   3200000
#define F_IN    512
#define HID     16
#define NCLS    40
#define SCAN_CHUNK 1024
#define NB ((N_NODES + SCAN_CHUNK - 1) / SCAN_CHUNK)  /* 98 */

#define NSLICE   8
#define SLICE_N  (N_NODES / NSLICE)   /* 12500 */
#define CHUNK_E  1024                 /* 256 threads x int4 == block coverage */
#define NCHUNK   (NEDGE / CHUNK_E)    /* 3125, exact */

typedef __bf16 bf16x8 __attribute__((ext_vector_type(8)));
typedef float floatx4 __attribute__((ext_vector_type(4)));

// ---------------- degree histogram (in-degree over dst) ----------------
__global__ void k_deg(const int* __restrict__ dst, int* __restrict__ deg) {
    int e = blockIdx.x * 256 + threadIdx.x;
    if (e < NEDGE) atomicAdd(&deg[dst[e]], 1);
}

// dinv = rsqrt(deg + 1)  (+1 = self loop)
__global__ void k_dinv(const int* __restrict__ deg, float* __restrict__ dinv) {
    int v = blockIdx.x * 256 + threadIdx.x;
    if (v < N_NODES) dinv[v] = rsqrtf((float)(deg[v] + 1));
}

// ---------------- hierarchical exclusive scan of deg -> rowptr ----------------
__global__ void k_scan_a(const int* __restrict__ deg, int* __restrict__ bsum) {
    int b = blockIdx.x, t = threadIdx.x;
    int idx = b * SCAN_CHUNK + t * 4;
    int s = 0;
    #pragma unroll
    for (int j = 0; j < 4; j++) s += (idx + j < N_NODES) ? deg[idx + j] : 0;
    __shared__ int red[256];
    red[t] = s; __syncthreads();
    for (int off = 128; off; off >>= 1) {
        if (t < off) red[t] += red[t + off];
        __syncthreads();
    }
    if (t == 0) bsum[b] = red[0];
}

__global__ void k_scan_b(const int* __restrict__ bsum, int* __restrict__ boff,
                         int* __restrict__ rowptr) {
    int t = threadIdx.x;
    int v = (t < NB) ? bsum[t] : 0;
    __shared__ int sc[128];
    sc[t] = v; __syncthreads();
    for (int off = 1; off < 128; off <<= 1) {
        int add = (t >= off) ? sc[t - off] : 0;
        __syncthreads();
        sc[t] += add;
        __syncthreads();
    }
    if (t < NB) boff[t] = sc[t] - v;       // exclusive block offset
    if (t == NB - 1) rowptr[N_NODES] = sc[t];  // total == NEDGE
}

__global__ void k_scan_c(const int* __restrict__ deg, const int* __restrict__ boff,
                         int* __restrict__ rowptr) {
    int b = blockIdx.x, t = threadIdx.x;
    int idx = b * SCAN_CHUNK + t * 4;
    int d0 = (idx + 0 < N_NODES) ? deg[idx + 0] : 0;
    int d1 = (idx + 1 < N_NODES) ? deg[idx + 1] : 0;
    int d2 = (idx + 2 < N_NODES) ? deg[idx + 2] : 0;
    int d3 = (idx + 3 < N_NODES) ? deg[idx + 3] : 0;
    int local = d0 + d1 + d2 + d3;
    __shared__ int sc[256];
    sc[t] = local; __syncthreads();
    for (int off = 1; off < 256; off <<= 1) {
        int add = (t >= off) ? sc[t - off] : 0;
        __syncthreads();
        sc[t] += add;
        __syncthreads();
    }
    int start = boff[b] + sc[t] - local;   // exclusive prefix
    if (idx + 0 < N_NODES) rowptr[idx + 0] = start;
    if (idx + 1 < N_NODES) rowptr[idx + 1] = start + d0;
    if (idx + 2 < N_NODES) rowptr[idx + 2] = start + d0 + d1;
    if (idx + 3 < N_NODES) rowptr[idx + 3] = start + d0 + d1 + d2;
}

// ---------------- CSR fill, XCD-sliced for write locality ----------------
// slice = blockIdx.x & 7 -> (round-robin dispatch) all blocks of a slice land
// on one XCD; that slice's ~1.6 MB col window stays in its 4 MB L2 and writes
// back once, full lines. Edge re-reads (8x dst) are served by the shared L3.
// Each block covers exactly CHUNK_E = 1024 edges (256 threads x int4).
__global__ void k_fill(const int* __restrict__ src, const int* __restrict__ dst,
                       const int* __restrict__ rowptr, int* __restrict__ fill,
                       int* __restrict__ col) {
    int slice = blockIdx.x & (NSLICE - 1);
    int chunk = blockIdx.x >> 3;
    int lo = slice * SLICE_N;
    int hi = lo + SLICE_N;
    int base = chunk * CHUNK_E + threadIdx.x * 4;   // always fully in-bounds
    int4 d4 = *(const int4*)(dst + base);
    int dd[4] = {d4.x, d4.y, d4.z, d4.w};
    #pragma unroll
    for (int j = 0; j < 4; j++) {
        int d = dd[j];
        if (d >= lo && d < hi) {
            int pos = rowptr[d] + atomicAdd(&fill[d], 1);
            col[pos] = src[base + j];
        }
    }
}

// ---------------- GEMM1: h1s = dinv * (x @ W1), bf16 MFMA hi/lo split ----------------
// wave handles 16 rows; K=512 in 16 chunks of 32; A from global, B(W1) from LDS frags.
__global__ __launch_bounds__(256) void k_gemm1(const float* __restrict__ x,
                                               const float* __restrict__ W1,
                                               const float* __restrict__ dinv,
                                               float* __restrict__ h1s) {
    __shared__ __bf16 wh[16 * 64 * 8];
    __shared__ __bf16 wl[16 * 64 * 8];
    int t = threadIdx.x;
    // stage W1 into MFMA B-fragment layout: entry e=(c*64+lane)*8+j holds
    // W1[k=c*32+(lane>>4)*8+j][n=lane&15]
    for (int e = t; e < 8192; e += 256) {
        int c = e >> 9, l = (e >> 3) & 63, j = e & 7;
        int k = c * 32 + ((l >> 4) << 3) + j;
        int n = l & 15;
        float wv = W1[k * HID + n];
        __bf16 h = (__bf16)wv;
        wh[e] = h;
        wl[e] = (__bf16)(wv - (float)h);
    }
    __syncthreads();

    int wave = t >> 6, lane = t & 63;
    int q = lane >> 4, m = lane & 15;
    int row0 = blockIdx.x * 64 + wave * 16;
    int rowa = row0 + m;
    if (rowa >= N_NODES) rowa = N_NODES - 1;  // clamp (stores are guarded)
    const float* xr = x + (size_t)rowa * F_IN + q * 8;

    floatx4 acc = {0.f, 0.f, 0.f, 0.f};
    #pragma unroll 4
    for (int c = 0; c < 16; c++) {
        float4 a0 = *(const float4*)(xr + c * 32);
        float4 a1 = *(const float4*)(xr + c * 32 + 4);
        float xv[8] = {a0.x, a0.y, a0.z, a0.w, a1.x, a1.y, a1.z, a1.w};
        bf16x8 ah, al;
        #pragma unroll
        for (int j = 0; j < 8; j++) {
            __bf16 h = (__bf16)xv[j];
            ah[j] = h;
            al[j] = (__bf16)(xv[j] - (float)h);
        }
        bf16x8 bh = *(const bf16x8*)&wh[(c * 64 + lane) * 8];
        bf16x8 bl = *(const bf16x8*)&wl[(c * 64 + lane) * 8];
        acc = __builtin_amdgcn_mfma_f32_16x16x32_bf16(ah, bh, acc, 0, 0, 0);
        acc = __builtin_amdgcn_mfma_f32_16x16x32_bf16(ah, bl, acc, 0, 0, 0);
        acc = __builtin_amdgcn_mfma_f32_16x16x32_bf16(al, bh, acc, 0, 0, 0);
    }
    // C/D layout: col = lane&15, row = (lane>>4)*4 + r   [m89-verified]
    #pragma unroll
    for (int r = 0; r < 4; r++) {
        int grow = row0 + q * 4 + r;
        if (grow < N_NODES) h1s[grow * HID + (lane & 15)] = dinv[grow] * acc[r];
    }
}

// ---------------- layer-1 aggregate + bias + relu; output pre-scaled by dinv ----------------
__global__ void k_agg1(const float* __restrict__ h1s, const int* __restrict__ rowptr,
                       const int* __restrict__ col, const float* __restrict__ dinv,
                       const float* __restrict__ b1, float* __restrict__ ys) {
    int g = blockIdx.x * 256 + threadIdx.x;   // grid == N*16 exactly
    int v = g >> 4, k = g & 15;
    float sum = h1s[v * HID + k];             // self loop (h1s already dinv-scaled)
    int beg = rowptr[v], end = rowptr[v + 1];
    int j = beg;
    for (; j + 1 < end; j += 2) {
        int c0 = col[j], c1 = col[j + 1];
        float g0 = h1s[c0 * HID + k];
        float g1 = h1s[c1 * HID + k];
        sum += g0 + g1;
    }
    if (j < end) sum += h1s[col[j] * HID + k];
    float dv = dinv[v];
    float val = fmaxf(dv * sum + b1[k], 0.f);
    ys[v * HID + k] = dv * val;               // pre-scale for layer 2
}

// ---------------- layer-2 aggregate + W2 (16->40) + bias + log_softmax ----------------
__global__ void k_agg2(const float* __restrict__ ys, const int* __restrict__ rowptr,
                       const int* __restrict__ col, const float* __restrict__ dinv,
                       const float* __restrict__ W2, const float* __restrict__ b2,
                       float* __restrict__ out) {
    __shared__ float w2s[HID * NCLS];
    __shared__ float b2s[NCLS];
    int t = threadIdx.x;
    for (int i = t; i < HID * NCLS; i += 256) w2s[i] = W2[i];
    if (t < NCLS) b2s[t] = b2[t];
    __syncthreads();

    int g = blockIdx.x * 256 + t;             // grid == N*16 exactly
    int v = g >> 4, l = g & 15;
    float sum = ys[v * HID + l];              // self loop
    int beg = rowptr[v], end = rowptr[v + 1];
    int j = beg;
    for (; j + 1 < end; j += 2) {
        int c0 = col[j], c1 = col[j + 1];
        float g0 = ys[c0 * HID + l];
        float g1 = ys[c1 * HID + l];
        sum += g0 + g1;
    }
    if (j < end) sum += ys[col[j] * HID + l];
    float tval = dinv[v] * sum;               // aggregated feature l

    // 16->40 matvec: lane l covers classes {l, l+16, l+32(l<8)}
    float acc0 = 0.f, acc1 = 0.f, acc2 = 0.f;
    #pragma unroll
    for (int k = 0; k < 16; k++) {
        float tk = __shfl(tval, k, 16);
        acc0 = fmaf(tk, w2s[k * NCLS + l], acc0);
        acc1 = fmaf(tk, w2s[k * NCLS + l + 16], acc1);
        if (l < 8) acc2 = fmaf(tk, w2s[k * NCLS + l + 32], acc2);
    }
    acc0 += b2s[l];
    acc1 += b2s[l + 16];
    float acc2b = (l < 8) ? (acc2 + b2s[l + 32]) : -1e30f;

    // group softmax over the 40 logits spread across 16 lanes
    float mx = fmaxf(fmaxf(acc0, acc1), acc2b);
    for (int off = 8; off; off >>= 1) mx = fmaxf(mx, __shfl_xor(mx, off, 16));
    float s = __expf(acc0 - mx) + __expf(acc1 - mx) + __expf(acc2b - mx);
    for (int off = 8; off; off >>= 1) s += __shfl_xor(s, off, 16);
    float lse = mx + __logf(s);

    out[v * NCLS + l] = acc0 - lse;
    out[v * NCLS + l + 16] = acc1 - lse;
    if (l < 8) out[v * NCLS + l + 32] = acc2b - lse;
}

extern "C" void kernel_launch(void* const* d_in, const int* in_sizes, int n_in,
                              void* d_out, int out_size, void* d_ws, size_t ws_size,
                              hipStream_t stream) {
    const float* x  = (const float*)d_in[0];
    const int*   ei = (const int*)d_in[1];
    const float* W1 = (const float*)d_in[2];
    const float* b1 = (const float*)d_in[3];
    const float* W2 = (const float*)d_in[4];
    const float* b2 = (const float*)d_in[5];
    float* out = (float*)d_out;
    const int* src = ei;
    const int* dst = ei + NEDGE;

    char* w = (char*)d_ws;
    size_t o = 0;
    auto alloc = [&](size_t bytes) -> char* {
        char* p = w + o;
        o += (bytes + 511) & ~(size_t)511;
        return p;
    };
    int*   deg    = (int*)alloc((size_t)N_NODES * 4);
    float* dinv   = (float*)alloc((size_t)N_NODES * 4);
    int*   rowptr = (int*)alloc((size_t)(N_NODES + 1) * 4);
    int*   fill   = (int*)alloc((size_t)N_NODES * 4);
    int*   bsum   = (int*)alloc((size_t)NB * 4);
    int*   boff   = (int*)alloc((size_t)NB * 4);
    int*   col    = (int*)alloc((size_t)NEDGE * 4);
    float* h1s    = (float*)alloc((size_t)N_NODES * HID * 4);
    float* ys     = (float*)alloc((size_t)N_NODES * HID * 4);

    hipMemsetAsync(deg, 0, (size_t)N_NODES * 4, stream);
    hipMemsetAsync(fill, 0, (size_t)N_NODES * 4, stream);

    k_deg<<<NEDGE / 256, 256, 0, stream>>>(dst, deg);
    k_dinv<<<(N_NODES + 255) / 256, 256, 0, stream>>>(deg, dinv);
    k_scan_a<<<NB, 256, 0, stream>>>(deg, bsum);
    k_scan_b<<<1, 128, 0, stream>>>(bsum, boff, rowptr);
    k_scan_c<<<NB, 256, 0, stream>>>(deg, boff, rowptr);
    k_fill<<<NCHUNK * NSLICE, 256, 0, stream>>>(src, dst, rowptr, fill, col);
    k_gemm1<<<(N_NODES + 63) / 64, 256, 0, stream>>>(x, W1, dinv, h1s);
    k_agg1<<<(N_NODES * HID) / 256, 256, 0, stream>>>(h1s, rowptr, col, dinv, b1, ys);
    k_agg2<<<(N_NODES * HID) / 256, 256, 0, stream>>>(ys, rowptr, col, dinv, W2, b2, out);
}